// Round 14
// baseline (715.548 us; speedup 1.0000x reference)
//
#include <hip/hip_runtime.h>

// ---------------------------------------------------------------------------
// FractalAttention: B=4, L=4096, D=1024, H=16, DH=64, S=4
//
//  sq_s = x @ (ws[s]@wq).T + (ws[s]@bq + bs[s])   (same for k,v)
//  1. convert x, ws, wo to bf16 (one fused kernel); transpose wq/wk/wv
//  2. fuse weights:  Wf[s*3+t] = ws[s] @ w_t   (12x 1024^3, gemm256 zmode=1)
//  3. fuse biases:   bf[s*3+t] = ws[s] @ b_t + bs[s]
//  4. per row-chunk: proj (12 batched, round-7 256^2 ring-4 reg-dbuf GEMM)
//     -> all-scale fused attention (rolled + LDS K/V double-buffer)
//  5. single final GEMM: out = comb @ wo.T + bo  (gemm256, f32 out)
//
// Proj-GEMM experiment ledger (6 structures, all 105-115us / 40-43% util;
// do not retry): m97-128^2 134us; 2-phase-256^2 115; merged-1-barrier 108.7;
// reg-dbuf 105.5 (BEST, current); +SGB graft 114 (-8%); 8-phase m201-port
// 111/40% (62% not reproduced at K=1024). Also: 2 blk/CU @256^2 impossible
// (acc=128 VGPR); gathered per-lane global loads serialize TA (192us);
// unrolled attn scale loop spills to 256 VGPR / 200MB scratch.
// ---------------------------------------------------------------------------

typedef unsigned short u16;
typedef __attribute__((ext_vector_type(8))) short s16x8;
typedef __attribute__((ext_vector_type(8))) unsigned short u16x8;
typedef __attribute__((ext_vector_type(4))) float f32x4;

#define MM 16384        // B*L
#define DDIM 1024
#define DDSQ 1048576ull // D*D

__device__ __forceinline__ u16 f2bf(float f) {
  unsigned u = __float_as_uint(f);
  u = (u + 0x7FFFu + ((u >> 16) & 1u)) >> 16;   // RNE
  return (u16)u;
}
__device__ __forceinline__ float b2f(u16 b) {
  return __uint_as_float(((unsigned)b) << 16);
}
__device__ __forceinline__ void gload_lds16(const void* g, void* l) {
  __builtin_amdgcn_global_load_lds(
      (const __attribute__((address_space(1))) void*)g,
      (__attribute__((address_space(3))) void*)l, 16, 0, 0);
}

// ---------------------------------------------------------------------------
// fused f32 -> bf16 convert for three arrays (grid-stride, float4 units)
// ---------------------------------------------------------------------------
__global__ __launch_bounds__(256) void k_cvt3(
    const float* __restrict__ a, u16* __restrict__ oa, int na,
    const float* __restrict__ b, u16* __restrict__ ob, int nb,
    const float* __restrict__ c, u16* __restrict__ oc, int nc) {
  int total = na + nb + nc;
  for (int i = blockIdx.x * 256 + threadIdx.x; i < total;
       i += gridDim.x * 256) {
    const float* src; u16* dst; int j = i;
    if (j < na)            { src = a; dst = oa; }
    else if ((j -= na) < nb) { src = b; dst = ob; }
    else                   { j -= nb; src = c; dst = oc; }
    float4 v = reinterpret_cast<const float4*>(src)[j];
    ushort4 o;
    o.x = f2bf(v.x); o.y = f2bf(v.y); o.z = f2bf(v.z); o.w = f2bf(v.w);
    reinterpret_cast<ushort4*>(dst)[j] = o;
  }
}

// ---------------------------------------------------------------------------
__global__ __launch_bounds__(256) void k_transpose_bf16(
    const float* __restrict__ wq, const float* __restrict__ wk,
    const float* __restrict__ wv, u16* __restrict__ out) {
  __shared__ float tile[32][33];
  const float* src = (blockIdx.z == 0) ? wq : (blockIdx.z == 1) ? wk : wv;
  u16* dst = out + (size_t)blockIdx.z * DDSQ;
  int tx = threadIdx.x, ty = threadIdx.y;
  int bx = blockIdx.x * 32, by = blockIdx.y * 32;
#pragma unroll
  for (int i = 0; i < 4; ++i)
    tile[ty + 8 * i][tx] = src[(size_t)(by + ty + 8 * i) * DDIM + bx + tx];
  __syncthreads();
#pragma unroll
  for (int i = 0; i < 4; ++i)
    dst[(size_t)(bx + ty + 8 * i) * DDIM + by + tx] = f2bf(tile[tx][ty + 8 * i]);
}

// ---------------------------------------------------------------------------
__global__ __launch_bounds__(256) void k_bias_fuse(
    const float* __restrict__ ws, const float* __restrict__ bq,
    const float* __restrict__ bk, const float* __restrict__ bv,
    const float* __restrict__ bs, float* __restrict__ bf) {
  int idx = blockIdx.y;
  int s = idx / 3, t = idx - s * 3;
  const float* bt = (t == 0) ? bq : (t == 1) ? bk : bv;
  int lane = threadIdx.x & 63, wid = threadIdx.x >> 6;
  int e = blockIdx.x * 4 + wid;
  const float* wr = ws + (size_t)s * DDSQ + (size_t)e * DDIM;
  float p = 0.f;
  for (int j = lane; j < DDIM; j += 64) p += wr[j] * bt[j];
#pragma unroll
  for (int off = 32; off > 0; off >>= 1) p += __shfl_xor(p, off);
  if (lane == 0) bf[idx * DDIM + e] = p + bs[s * DDIM + e];
}

// ---------------------------------------------------------------------------
// Round-7 256x256 pipelined GEMM (16x16 MFMA, ring-4, reg-dbuf ds_reads).
// Known good: 105.5us proj-class, MfmaUtil 43%, conflicts 0.
// Used for weight-fuse (zmode=1), proj, and final.
// ---------------------------------------------------------------------------
template <typename OutT>
__global__ __launch_bounds__(512, 1) void k_gemm256(
    const u16* __restrict__ A, const u16* __restrict__ B, OutT* __restrict__ C,
    const float* __restrict__ bias, int M, int N, int K,
    size_t za, size_t zb, size_t zc, size_t zbias, int nbx, int zmode) {
  __shared__ u16 lds[4][2][8192];   // [ring][A/B][256*32]

  int z = blockIdx.x / nbx;
  int nb = blockIdx.x - z * nbx;
  const u16* Ag; const u16* Bg;
  if (zmode == 1) { Ag = A + (size_t)(z / 3) * za; Bg = B + (size_t)(z % 3) * zb; }
  else            { Ag = A + (size_t)z * za;       Bg = B + (size_t)z * zb; }
  OutT* Cg = C + (size_t)z * zc;
  const float* biasz = bias ? (bias + (size_t)z * zbias) : nullptr;

  int m0 = blockIdx.y * 256, n0 = nb * 256;
  int tid = threadIdx.x;
  int lane = tid & 63, wid = tid >> 6;
  int wm = wid >> 2, wn = wid & 3;
  int NT = K >> 5;

  int scb = ((lane & 3) * 16) ^ (((lane >> 3) & 3) << 4);
  const char* srcA[2]; const char* srcB[2]; int ldsc[2];
#pragma unroll
  for (int r = 0; r < 2; ++r) {
    int c = r * 8 + wid;
    int row = c * 16 + (lane >> 2);
    srcA[r] = (const char*)Ag + ((size_t)(m0 + row) * K) * 2 + scb;
    srcB[r] = (const char*)Bg + ((size_t)(n0 + row) * K) * 2 + scb;
    ldsc[r] = c * 1024;
  }
  char* lbase = (char*)&lds[0][0][0];

  int fxor = ((lane >> 4) * 16) ^ (((lane >> 1) & 3) << 4);
  int aoff = (wm * 128 + (lane & 15)) * 64 + fxor;
  int boff = (wn * 64 + (lane & 15)) * 64 + fxor;

  f32x4 acc[8][4] = {};
  s16x8 cA0[4], cA1[4], cB[4];
  s16x8 nA0[4], nA1[4], nB[4];

#define STAGE_A(kt, rg)                                                   \
  {                                                                       \
    _Pragma("unroll") for (int r = 0; r < 2; ++r)                         \
        gload_lds16(srcA[r] + (size_t)(kt) * 64,                          \
                    lbase + (rg) * 32768 + ldsc[r]);                      \
  }
#define STAGE_B(kt, rg)                                                   \
  {                                                                       \
    _Pragma("unroll") for (int r = 0; r < 2; ++r)                         \
        gload_lds16(srcB[r] + (size_t)(kt) * 64,                          \
                    lbase + (rg) * 32768 + 16384 + ldsc[r]);              \
  }
#define SUBITER(C0, C1, CBv, N0, N1, NBv, tcur)                           \
  {                                                                       \
    asm volatile("s_waitcnt vmcnt(4)" ::: "memory");                      \
    asm volatile("s_barrier" ::: "memory");                               \
    int tn = (tcur) + 1 < NT ? (tcur) + 1 : NT - 1;                       \
    const char* bA = lbase + (tn & 3) * 32768;                            \
    const char* bB = bA + 16384;                                          \
    _Pragma("unroll") for (int i = 0; i < 4; ++i)                         \
        NBv[i] = *(const s16x8*)(bB + boff + i * 1024);                   \
    _Pragma("unroll") for (int i = 0; i < 4; ++i)                         \
        N0[i] = *(const s16x8*)(bA + aoff + i * 1024);                    \
    _Pragma("unroll") for (int i = 0; i < 4; ++i)                         \
        N1[i] = *(const s16x8*)(bA + aoff + 4096 + i * 1024);             \
    int ts = (tcur) + 3 < NT ? (tcur) + 3 : NT - 1;                       \
    int rgs = ((tcur) + 3) & 3;                                           \
    STAGE_A(ts, rgs); STAGE_B(ts, rgs);                                   \
    __builtin_amdgcn_s_setprio(1);                                        \
    _Pragma("unroll") for (int mi = 0; mi < 4; ++mi)                      \
      _Pragma("unroll") for (int ni = 0; ni < 4; ++ni)                    \
          acc[mi][ni] = __builtin_amdgcn_mfma_f32_16x16x32_bf16(          \
              C0[mi], CBv[ni], acc[mi][ni], 0, 0, 0);                     \
    _Pragma("unroll") for (int mi = 0; mi < 4; ++mi)                      \
      _Pragma("unroll") for (int ni = 0; ni < 4; ++ni)                    \
          acc[mi + 4][ni] = __builtin_amdgcn_mfma_f32_16x16x32_bf16(      \
              C1[mi], CBv[ni], acc[mi + 4][ni], 0, 0, 0);                 \
    __builtin_amdgcn_s_setprio(0);                                        \
  }

  STAGE_A(0, 0); STAGE_B(0, 0);
  STAGE_A(1, 1); STAGE_B(1, 1);
  STAGE_A(2, 2); STAGE_B(2, 2);
  asm volatile("s_waitcnt vmcnt(8)" ::: "memory");
  asm volatile("s_barrier" ::: "memory");
  {
    const char* bA = lbase;
    const char* bB = bA + 16384;
#pragma unroll
    for (int i = 0; i < 4; ++i) cB[i]  = *(const s16x8*)(bB + boff + i * 1024);
#pragma unroll
    for (int i = 0; i < 4; ++i) cA0[i] = *(const s16x8*)(bA + aoff + i * 1024);
#pragma unroll
    for (int i = 0; i < 4; ++i)
      cA1[i] = *(const s16x8*)(bA + aoff + 4096 + i * 1024);
  }

  for (int t = 0; t < NT; t += 2) {
    SUBITER(cA0, cA1, cB, nA0, nA1, nB, t);
    SUBITER(nA0, nA1, nB, cA0, cA1, cB, t + 1);
  }
#undef SUBITER
#undef STAGE_A
#undef STAGE_B

  asm volatile("s_waitcnt vmcnt(0)" ::: "memory");

#pragma unroll
  for (int mi = 0; mi < 8; ++mi) {
#pragma unroll
    for (int ni = 0; ni < 4; ++ni) {
      int colg = n0 + wn * 64 + ni * 16 + (lane & 15);
      float badd = biasz ? biasz[colg] : 0.f;
#pragma unroll
      for (int r = 0; r < 4; ++r) {
        int rowg = m0 + wm * 128 + mi * 16 + ((lane >> 4) << 2) + r;
        float v = acc[mi][ni][r] + badd;
        if constexpr (sizeof(OutT) == 2) Cg[(size_t)rowg * N + colg] = f2bf(v);
        else                             Cg[(size_t)rowg * N + colg] = v;
      }
    }
  }
}

// ---------------------------------------------------------------------------
// per-position head-mix attention, ALL 4 scales fused. (round-12 version:
// rolled loop + LDS K/V double-buffer, vmcnt(6). Do not unroll.)
// ---------------------------------------------------------------------------
__global__ __launch_bounds__(256) void k_attn_all(
    const u16* __restrict__ proj, u16* __restrict__ outbf,
    const float* __restrict__ sl, int rows) {
  __shared__ u16 kv[4][2][2][1024];   // [wave][buf][K/V][1024] = 32 KB
  int lane = threadIdx.x & 63, wid = threadIdx.x >> 6;
  int row = blockIdx.x * 4 + wid;
  int h = lane >> 2, dq = lane & 3;
  int doff = h * 64 + dq * 16;

  float l0 = sl[0], l1 = sl[1], l2 = sl[2], l3 = sl[3];
  float lm = fmaxf(fmaxf(l0, l1), fmaxf(l2, l3));
  float e0 = __expf(l0 - lm), e1 = __expf(l1 - lm), e2 = __expf(l2 - lm),
        e3 = __expf(l3 - lm);
  float esum = e0 + e1 + e2 + e3;
  float wsc4[4] = {e0 / esum, e1 / esum, e2 / esum, e3 / esum};

#define KV_ISSUE(s, buf)                                                   \
  {                                                                        \
    const u16* kr = proj + ((size_t)(3 * (s) + 1) * rows + row) * DDIM;    \
    const u16* vr = proj + ((size_t)(3 * (s) + 2) * rows + row) * DDIM;    \
    gload_lds16(kr + lane * 8,       &kv[wid][buf][0][0]);                 \
    gload_lds16(kr + 512 + lane * 8, &kv[wid][buf][0][512]);               \
    gload_lds16(vr + lane * 8,       &kv[wid][buf][1][0]);                 \
    gload_lds16(vr + 512 + lane * 8, &kv[wid][buf][1][512]);               \
  }

  KV_ISSUE(0, 0);   // prologue: scale 0 -> buf 0

  float acc[16];
#pragma unroll
  for (int i = 0; i < 16; ++i) acc[i] = 0.f;

  for (int s = 0; s < 4; ++s) {
    int buf = s & 1;

    const u16* qr = proj + ((size_t)(3 * s) * rows + row) * DDIM + doff;
    u16x8 q0 = *reinterpret_cast<const u16x8*>(qr);
    u16x8 q1 = *reinterpret_cast<const u16x8*>(qr + 8);

    if (s < 3) KV_ISSUE(s + 1, buf ^ 1);

    if (s < 3) asm volatile("s_waitcnt vmcnt(6)" ::: "memory");
    else       asm volatile("s_waitcnt vmcnt(0)" ::: "memory");

    float qf[16];
#pragma unroll
    for (int i = 0; i < 8; ++i) {
      qf[i]     = b2f(q0[i]) * 0.125f;
      qf[8 + i] = b2f(q1[i]) * 0.125f;
    }

    float sc[16];
#pragma unroll
    for (int g = 0; g < 16; ++g) {
      const u16* kp = &kv[wid][buf][0][g * 64 + dq * 16];
      u16x8 k0 = *reinterpret_cast<const u16x8*>(kp);
      u16x8 k1 = *reinterpret_cast<const u16x8*>(kp + 8);
      float d = 0.f;
#pragma unroll
      for (int i = 0; i < 8; ++i) d = fmaf(qf[i], b2f(k0[i]), d);
#pragma unroll
      for (int i = 0; i < 8; ++i) d = fmaf(qf[8 + i], b2f(k1[i]), d);
      d += __shfl_xor(d, 1);
      d += __shfl_xor(d, 2);
      sc[g] = d;
    }

    float mx = sc[0];
#pragma unroll
    for (int g = 1; g < 16; ++g) mx = fmaxf(mx, sc[g]);
    float sum = 0.f;
#pragma unroll
    for (int g = 0; g < 16; ++g) { sc[g] = __expf(sc[g] - mx); sum += sc[g]; }
    float inv = wsc4[s] / sum;
#pragma unroll
    for (int g = 0; g < 16; ++g) sc[g] *= inv;

#pragma unroll
    for (int g = 0; g < 16; ++g) {
      float a = sc[g];
      const u16* vp = &kv[wid][buf][1][g * 64 + dq * 16];
      u16x8 v0 = *reinterpret_cast<const u16x8*>(vp);
      u16x8 v1 = *reinterpret_cast<const u16x8*>(vp + 8);
#pragma unroll
      for (int i = 0; i < 8; ++i) {
        acc[i]     = fmaf(a, b2f(v0[i]), acc[i]);
        acc[8 + i] = fmaf(a, b2f(v1[i]), acc[8 + i]);
      }
    }
  }
#undef KV_ISSUE

  u16* op = outbf + (size_t)row * DDIM + doff;
  u16x8 o0, o1;
#pragma unroll
  for (int i = 0; i < 8; ++i) {
    o0[i] = f2bf(acc[i]);
    o1[i] = f2bf(acc[8 + i]);
  }
  *reinterpret_cast<u16x8*>(op) = o0;
  *reinterpret_cast<u16x8*>(op + 8) = o1;
}

// ---------------------------------------------------------------------------
extern "C" void kernel_launch(void* const* d_in, const int* in_sizes, int n_in,
                              void* d_out, int out_size, void* d_ws,
                              size_t ws_size, hipStream_t stream) {
  const float* x  = (const float*)d_in[0];
  const float* sl = (const float*)d_in[1];
  const float* wq = (const float*)d_in[2];
  const float* bq = (const float*)d_in[3];
  const float* wk = (const float*)d_in[4];
  const float* bk = (const float*)d_in[5];
  const float* wv = (const float*)d_in[6];
  const float* bv = (const float*)d_in[7];
  const float* wo = (const float*)d_in[8];
  const float* bo = (const float*)d_in[9];
  const float* ws = (const float*)d_in[10];
  const float* bs = (const float*)d_in[11];
  float* out = (float*)d_out;

  char* wsb = (char*)d_ws;
  size_t off = 0;
  u16* xbf    = (u16*)(wsb + off); off += (size_t)MM * DDIM * 2;   // 32 MB
  u16* wfus   = (u16*)(wsb + off); off += 12ull * DDSQ * 2;        // 24 MB
  u16* wobf   = (u16*)(wsb + off); off += DDSQ * 2;                // 2 MB
  float* bfus = (float*)(wsb + off); off += 65536;                 // 48 KB + pad
  u16* combc  = (u16*)(wsb + off); off += (size_t)MM * DDIM * 2;   // 32 MB
  char* dynr  = wsb + off;
  size_t fixed = off;

  int chunk = 4096;
  while (chunk > 1024 && fixed + (size_t)12 * chunk * DDIM * 2 > ws_size)
    chunk >>= 1;
  u16* projc = (u16*)dynr;
  u16* wtT  = (u16*)dynr;                      // prefuse overlay, 6 MB
  u16* wsbf = (u16*)(dynr + 3ull * DDSQ * 2);  // prefuse overlay, 8 MB

  // fused conversions: x, ws, wo -> bf16 (one kernel)
  k_cvt3<<<2048, 256, 0, stream>>>(
      x, xbf, MM * DDIM / 4,
      ws, wsbf, (int)(4 * DDSQ / 4),
      wo, wobf, (int)(DDSQ / 4));

  k_transpose_bf16<<<dim3(32, 32, 3), dim3(32, 8), 0, stream>>>(wq, wk, wv, wtT);
  k_bias_fuse<<<dim3(256, 12), 256, 0, stream>>>(ws, bq, bk, bv, bs, bfus);

  // fused weights: Wf[s*3+t] = ws_bf[s] @ wtT[t]^T  (pipelined, zmode=1)
  k_gemm256<u16><<<dim3(48, 4), 512, 0, stream>>>(
      wsbf, wtT, wfus, nullptr, 1024, 1024, 1024, DDSQ, DDSQ, DDSQ, 0, 4, 1);

  // chunked: proj (12 batched, round-7 256^2 GEMM) -> fused attention
  int nchunks = MM / chunk;
  for (int c = 0; c < nchunks; ++c) {
    const u16* xa = xbf + (size_t)c * chunk * DDIM;
    k_gemm256<u16><<<dim3(48, chunk / 256), 512, 0, stream>>>(
        xa, wfus, projc, bfus, chunk, 1024, 1024,
        0, DDSQ, (size_t)chunk * DDIM, DDIM, 4, 0);
    k_attn_all<<<dim3(chunk / 4), 256, 0, stream>>>(
        projc, combc + (size_t)c * chunk * DDIM, sl, chunk);
  }

  // single final GEMM: out = comb_bf @ wo^T + bo  (fp32 out)
  k_gemm256<float><<<dim3(4, 64), 512, 0, stream>>>(
      combc, wobf, out, bo, MM, 1024, 1024, 0, 0, 0, 0, 4, 0);
}

// Round 15
// 683.940 us; speedup vs baseline: 1.0462x; 1.0462x over previous
//
#include <hip/hip_runtime.h>

// ---------------------------------------------------------------------------
// FractalAttention: B=4, L=4096, D=1024, H=16, DH=64, S=4
//
//  sq_s = x @ (ws[s]@wq).T + (ws[s]@bq + bs[s])   (same for k,v)
//  1. convert x, ws, wo to bf16 (one fused kernel); transpose wq/wk/wv
//  2. fuse weights:  Wf[s*3+t] = ws[s] @ w_t   (gemm256<ZMODE=1>)
//  3. fuse biases:   bf[s*3+t] = ws[s] @ b_t + bs[s]
//  4. per row-chunk: proj (12 batched, gemm256<ZMODE=0> — round-7/12
//     structure, bit-identical instantiation) -> all-scale fused attention
//     (rolled + LDS K/V double-buffer)
//  5. single final GEMM: out = comb @ wo.T + bo  (gemm256<float,0>)
//
// Experiment ledger (do not retry):
//  - proj structures, all 105-115us / 38-43% util: m97-128^2 134; 2-phase
//    256^2 115; merged-1-barrier 108.7; reg-dbuf 105.5 (BEST); +SGB 114;
//    8-phase m201-port 111/40%.
//  - RUNTIME zmode param on gemm256: +10%/dispatch codegen tax (r14) —
//    compile-time template only.
//  - 2 blk/CU @256^2 impossible (acc=128 VGPR > cap at 4 waves/EU).
//  - per-lane gathered global loads serialize TA (~2000cyc/tile, r11).
//  - unrolled attn scale loop spills (256 VGPR / 200MB scratch, r6/r8).
// ---------------------------------------------------------------------------

typedef unsigned short u16;
typedef __attribute__((ext_vector_type(8))) short s16x8;
typedef __attribute__((ext_vector_type(8))) unsigned short u16x8;
typedef __attribute__((ext_vector_type(4))) float f32x4;

#define MM 16384        // B*L
#define DDIM 1024
#define DDSQ 1048576ull // D*D

__device__ __forceinline__ u16 f2bf(float f) {
  unsigned u = __float_as_uint(f);
  u = (u + 0x7FFFu + ((u >> 16) & 1u)) >> 16;   // RNE
  return (u16)u;
}
__device__ __forceinline__ float b2f(u16 b) {
  return __uint_as_float(((unsigned)b) << 16);
}
__device__ __forceinline__ void gload_lds16(const void* g, void* l) {
  __builtin_amdgcn_global_load_lds(
      (const __attribute__((address_space(1))) void*)g,
      (__attribute__((address_space(3))) void*)l, 16, 0, 0);
}

// ---------------------------------------------------------------------------
// fused f32 -> bf16 convert for three arrays (grid-stride, float4 units)
// ---------------------------------------------------------------------------
__global__ __launch_bounds__(256) void k_cvt3(
    const float* __restrict__ a, u16* __restrict__ oa, int na,
    const float* __restrict__ b, u16* __restrict__ ob, int nb,
    const float* __restrict__ c, u16* __restrict__ oc, int nc) {
  int total = na + nb + nc;
  for (int i = blockIdx.x * 256 + threadIdx.x; i < total;
       i += gridDim.x * 256) {
    const float* src; u16* dst; int j = i;
    if (j < na)            { src = a; dst = oa; }
    else if ((j -= na) < nb) { src = b; dst = ob; }
    else                   { j -= nb; src = c; dst = oc; }
    float4 v = reinterpret_cast<const float4*>(src)[j];
    ushort4 o;
    o.x = f2bf(v.x); o.y = f2bf(v.y); o.z = f2bf(v.z); o.w = f2bf(v.w);
    reinterpret_cast<ushort4*>(dst)[j] = o;
  }
}

// ---------------------------------------------------------------------------
__global__ __launch_bounds__(256) void k_transpose_bf16(
    const float* __restrict__ wq, const float* __restrict__ wk,
    const float* __restrict__ wv, u16* __restrict__ out) {
  __shared__ float tile[32][33];
  const float* src = (blockIdx.z == 0) ? wq : (blockIdx.z == 1) ? wk : wv;
  u16* dst = out + (size_t)blockIdx.z * DDSQ;
  int tx = threadIdx.x, ty = threadIdx.y;
  int bx = blockIdx.x * 32, by = blockIdx.y * 32;
#pragma unroll
  for (int i = 0; i < 4; ++i)
    tile[ty + 8 * i][tx] = src[(size_t)(by + ty + 8 * i) * DDIM + bx + tx];
  __syncthreads();
#pragma unroll
  for (int i = 0; i < 4; ++i)
    dst[(size_t)(bx + ty + 8 * i) * DDIM + by + tx] = f2bf(tile[tx][ty + 8 * i]);
}

// ---------------------------------------------------------------------------
__global__ __launch_bounds__(256) void k_bias_fuse(
    const float* __restrict__ ws, const float* __restrict__ bq,
    const float* __restrict__ bk, const float* __restrict__ bv,
    const float* __restrict__ bs, float* __restrict__ bf) {
  int idx = blockIdx.y;
  int s = idx / 3, t = idx - s * 3;
  const float* bt = (t == 0) ? bq : (t == 1) ? bk : bv;
  int lane = threadIdx.x & 63, wid = threadIdx.x >> 6;
  int e = blockIdx.x * 4 + wid;
  const float* wr = ws + (size_t)s * DDSQ + (size_t)e * DDIM;
  float p = 0.f;
  for (int j = lane; j < DDIM; j += 64) p += wr[j] * bt[j];
#pragma unroll
  for (int off = 32; off > 0; off >>= 1) p += __shfl_xor(p, off);
  if (lane == 0) bf[idx * DDIM + e] = p + bs[s * DDIM + e];
}

// ---------------------------------------------------------------------------
// Round-7/12 256x256 pipelined GEMM (16x16 MFMA, ring-4, reg-dbuf ds_reads).
// Known good: 105.5us proj-class, MfmaUtil 43%, conflicts 0.
// ZMODE is COMPILE-TIME (r14 lesson: runtime zmode cost 10%/dispatch).
// ZMODE==0: A += z*za, B += z*zb, bias REQUIRED (read unconditionally).
// ZMODE==1: A += (z/3)*za, B += (z%3)*zb, bias compile-time-absent.
// ---------------------------------------------------------------------------
template <typename OutT, int ZMODE>
__global__ __launch_bounds__(512, 1) void k_gemm256(
    const u16* __restrict__ A, const u16* __restrict__ B, OutT* __restrict__ C,
    const float* __restrict__ bias, int M, int N, int K,
    size_t za, size_t zb, size_t zc, size_t zbias, int nbx) {
  __shared__ u16 lds[4][2][8192];   // [ring][A/B][256*32]

  int z = blockIdx.x / nbx;
  int nb = blockIdx.x - z * nbx;
  const u16* Ag; const u16* Bg;
  if constexpr (ZMODE == 1) {
    Ag = A + (size_t)(z / 3) * za; Bg = B + (size_t)(z % 3) * zb;
  } else {
    Ag = A + (size_t)z * za;       Bg = B + (size_t)z * zb;
  }
  OutT* Cg = C + (size_t)z * zc;
  const float* biasz = nullptr;
  if constexpr (ZMODE == 0) biasz = bias + (size_t)z * zbias;

  int m0 = blockIdx.y * 256, n0 = nb * 256;
  int tid = threadIdx.x;
  int lane = tid & 63, wid = tid >> 6;
  int wm = wid >> 2, wn = wid & 3;
  int NT = K >> 5;

  int scb = ((lane & 3) * 16) ^ (((lane >> 3) & 3) << 4);
  const char* srcA[2]; const char* srcB[2]; int ldsc[2];
#pragma unroll
  for (int r = 0; r < 2; ++r) {
    int c = r * 8 + wid;
    int row = c * 16 + (lane >> 2);
    srcA[r] = (const char*)Ag + ((size_t)(m0 + row) * K) * 2 + scb;
    srcB[r] = (const char*)Bg + ((size_t)(n0 + row) * K) * 2 + scb;
    ldsc[r] = c * 1024;
  }
  char* lbase = (char*)&lds[0][0][0];

  int fxor = ((lane >> 4) * 16) ^ (((lane >> 1) & 3) << 4);
  int aoff = (wm * 128 + (lane & 15)) * 64 + fxor;
  int boff = (wn * 64 + (lane & 15)) * 64 + fxor;

  f32x4 acc[8][4] = {};
  s16x8 cA0[4], cA1[4], cB[4];
  s16x8 nA0[4], nA1[4], nB[4];

#define STAGE_A(kt, rg)                                                   \
  {                                                                       \
    _Pragma("unroll") for (int r = 0; r < 2; ++r)                         \
        gload_lds16(srcA[r] + (size_t)(kt) * 64,                          \
                    lbase + (rg) * 32768 + ldsc[r]);                      \
  }
#define STAGE_B(kt, rg)                                                   \
  {                                                                       \
    _Pragma("unroll") for (int r = 0; r < 2; ++r)                         \
        gload_lds16(srcB[r] + (size_t)(kt) * 64,                          \
                    lbase + (rg) * 32768 + 16384 + ldsc[r]);              \
  }
#define SUBITER(C0, C1, CBv, N0, N1, NBv, tcur)                           \
  {                                                                       \
    asm volatile("s_waitcnt vmcnt(4)" ::: "memory");                      \
    asm volatile("s_barrier" ::: "memory");                               \
    int tn = (tcur) + 1 < NT ? (tcur) + 1 : NT - 1;                       \
    const char* bA = lbase + (tn & 3) * 32768;                            \
    const char* bB = bA + 16384;                                          \
    _Pragma("unroll") for (int i = 0; i < 4; ++i)                         \
        NBv[i] = *(const s16x8*)(bB + boff + i * 1024);                   \
    _Pragma("unroll") for (int i = 0; i < 4; ++i)                         \
        N0[i] = *(const s16x8*)(bA + aoff + i * 1024);                    \
    _Pragma("unroll") for (int i = 0; i < 4; ++i)                         \
        N1[i] = *(const s16x8*)(bA + aoff + 4096 + i * 1024);             \
    int ts = (tcur) + 3 < NT ? (tcur) + 3 : NT - 1;                       \
    int rgs = ((tcur) + 3) & 3;                                           \
    STAGE_A(ts, rgs); STAGE_B(ts, rgs);                                   \
    __builtin_amdgcn_s_setprio(1);                                        \
    _Pragma("unroll") for (int mi = 0; mi < 4; ++mi)                      \
      _Pragma("unroll") for (int ni = 0; ni < 4; ++ni)                    \
          acc[mi][ni] = __builtin_amdgcn_mfma_f32_16x16x32_bf16(          \
              C0[mi], CBv[ni], acc[mi][ni], 0, 0, 0);                     \
    _Pragma("unroll") for (int mi = 0; mi < 4; ++mi)                      \
      _Pragma("unroll") for (int ni = 0; ni < 4; ++ni)                    \
          acc[mi + 4][ni] = __builtin_amdgcn_mfma_f32_16x16x32_bf16(      \
              C1[mi], CBv[ni], acc[mi + 4][ni], 0, 0, 0);                 \
    __builtin_amdgcn_s_setprio(0);                                        \
  }

  STAGE_A(0, 0); STAGE_B(0, 0);
  STAGE_A(1, 1); STAGE_B(1, 1);
  STAGE_A(2, 2); STAGE_B(2, 2);
  asm volatile("s_waitcnt vmcnt(8)" ::: "memory");
  asm volatile("s_barrier" ::: "memory");
  {
    const char* bA = lbase;
    const char* bB = bA + 16384;
#pragma unroll
    for (int i = 0; i < 4; ++i) cB[i]  = *(const s16x8*)(bB + boff + i * 1024);
#pragma unroll
    for (int i = 0; i < 4; ++i) cA0[i] = *(const s16x8*)(bA + aoff + i * 1024);
#pragma unroll
    for (int i = 0; i < 4; ++i)
      cA1[i] = *(const s16x8*)(bA + aoff + 4096 + i * 1024);
  }

  for (int t = 0; t < NT; t += 2) {
    SUBITER(cA0, cA1, cB, nA0, nA1, nB, t);
    SUBITER(nA0, nA1, nB, cA0, cA1, cB, t + 1);
  }
#undef SUBITER
#undef STAGE_A
#undef STAGE_B

  asm volatile("s_waitcnt vmcnt(0)" ::: "memory");

#pragma unroll
  for (int mi = 0; mi < 8; ++mi) {
#pragma unroll
    for (int ni = 0; ni < 4; ++ni) {
      int colg = n0 + wn * 64 + ni * 16 + (lane & 15);
      float badd;
      if constexpr (ZMODE == 0) badd = biasz[colg];
      else                      badd = 0.f;
#pragma unroll
      for (int r = 0; r < 4; ++r) {
        int rowg = m0 + wm * 128 + mi * 16 + ((lane >> 4) << 2) + r;
        float v = acc[mi][ni][r] + badd;
        if constexpr (sizeof(OutT) == 2) Cg[(size_t)rowg * N + colg] = f2bf(v);
        else                             Cg[(size_t)rowg * N + colg] = v;
      }
    }
  }
}

// ---------------------------------------------------------------------------
// per-position head-mix attention, ALL 4 scales fused. (round-12 version:
// rolled loop + LDS K/V double-buffer, vmcnt(6). Do not unroll.)
// ---------------------------------------------------------------------------
__global__ __launch_bounds__(256) void k_attn_all(
    const u16* __restrict__ proj, u16* __restrict__ outbf,
    const float* __restrict__ sl, int rows) {
  __shared__ u16 kv[4][2][2][1024];   // [wave][buf][K/V][1024] = 32 KB
  int lane = threadIdx.x & 63, wid = threadIdx.x >> 6;
  int row = blockIdx.x * 4 + wid;
  int h = lane >> 2, dq = lane & 3;
  int doff = h * 64 + dq * 16;

  float l0 = sl[0], l1 = sl[1], l2 = sl[2], l3 = sl[3];
  float lm = fmaxf(fmaxf(l0, l1), fmaxf(l2, l3));
  float e0 = __expf(l0 - lm), e1 = __expf(l1 - lm), e2 = __expf(l2 - lm),
        e3 = __expf(l3 - lm);
  float esum = e0 + e1 + e2 + e3;
  float wsc4[4] = {e0 / esum, e1 / esum, e2 / esum, e3 / esum};

#define KV_ISSUE(s, buf)                                                   \
  {                                                                        \
    const u16* kr = proj + ((size_t)(3 * (s) + 1) * rows + row) * DDIM;    \
    const u16* vr = proj + ((size_t)(3 * (s) + 2) * rows + row) * DDIM;    \
    gload_lds16(kr + lane * 8,       &kv[wid][buf][0][0]);                 \
    gload_lds16(kr + 512 + lane * 8, &kv[wid][buf][0][512]);               \
    gload_lds16(vr + lane * 8,       &kv[wid][buf][1][0]);                 \
    gload_lds16(vr + 512 + lane * 8, &kv[wid][buf][1][512]);               \
  }

  KV_ISSUE(0, 0);   // prologue: scale 0 -> buf 0

  float acc[16];
#pragma unroll
  for (int i = 0; i < 16; ++i) acc[i] = 0.f;

  for (int s = 0; s < 4; ++s) {
    int buf = s & 1;

    const u16* qr = proj + ((size_t)(3 * s) * rows + row) * DDIM + doff;
    u16x8 q0 = *reinterpret_cast<const u16x8*>(qr);
    u16x8 q1 = *reinterpret_cast<const u16x8*>(qr + 8);

    if (s < 3) KV_ISSUE(s + 1, buf ^ 1);

    if (s < 3) asm volatile("s_waitcnt vmcnt(6)" ::: "memory");
    else       asm volatile("s_waitcnt vmcnt(0)" ::: "memory");

    float qf[16];
#pragma unroll
    for (int i = 0; i < 8; ++i) {
      qf[i]     = b2f(q0[i]) * 0.125f;
      qf[8 + i] = b2f(q1[i]) * 0.125f;
    }

    float sc[16];
#pragma unroll
    for (int g = 0; g < 16; ++g) {
      const u16* kp = &kv[wid][buf][0][g * 64 + dq * 16];
      u16x8 k0 = *reinterpret_cast<const u16x8*>(kp);
      u16x8 k1 = *reinterpret_cast<const u16x8*>(kp + 8);
      float d = 0.f;
#pragma unroll
      for (int i = 0; i < 8; ++i) d = fmaf(qf[i], b2f(k0[i]), d);
#pragma unroll
      for (int i = 0; i < 8; ++i) d = fmaf(qf[8 + i], b2f(k1[i]), d);
      d += __shfl_xor(d, 1);
      d += __shfl_xor(d, 2);
      sc[g] = d;
    }

    float mx = sc[0];
#pragma unroll
    for (int g = 1; g < 16; ++g) mx = fmaxf(mx, sc[g]);
    float sum = 0.f;
#pragma unroll
    for (int g = 0; g < 16; ++g) { sc[g] = __expf(sc[g] - mx); sum += sc[g]; }
    float inv = wsc4[s] / sum;
#pragma unroll
    for (int g = 0; g < 16; ++g) sc[g] *= inv;

#pragma unroll
    for (int g = 0; g < 16; ++g) {
      float a = sc[g];
      const u16* vp = &kv[wid][buf][1][g * 64 + dq * 16];
      u16x8 v0 = *reinterpret_cast<const u16x8*>(vp);
      u16x8 v1 = *reinterpret_cast<const u16x8*>(vp + 8);
#pragma unroll
      for (int i = 0; i < 8; ++i) {
        acc[i]     = fmaf(a, b2f(v0[i]), acc[i]);
        acc[8 + i] = fmaf(a, b2f(v1[i]), acc[8 + i]);
      }
    }
  }
#undef KV_ISSUE

  u16* op = outbf + (size_t)row * DDIM + doff;
  u16x8 o0, o1;
#pragma unroll
  for (int i = 0; i < 8; ++i) {
    o0[i] = f2bf(acc[i]);
    o1[i] = f2bf(acc[8 + i]);
  }
  *reinterpret_cast<u16x8*>(op) = o0;
  *reinterpret_cast<u16x8*>(op + 8) = o1;
}

// ---------------------------------------------------------------------------
extern "C" void kernel_launch(void* const* d_in, const int* in_sizes, int n_in,
                              void* d_out, int out_size, void* d_ws,
                              size_t ws_size, hipStream_t stream) {
  const float* x  = (const float*)d_in[0];
  const float* sl = (const float*)d_in[1];
  const float* wq = (const float*)d_in[2];
  const float* bq = (const float*)d_in[3];
  const float* wk = (const float*)d_in[4];
  const float* bk = (const float*)d_in[5];
  const float* wv = (const float*)d_in[6];
  const float* bv = (const float*)d_in[7];
  const float* wo = (const float*)d_in[8];
  const float* bo = (const float*)d_in[9];
  const float* ws = (const float*)d_in[10];
  const float* bs = (const float*)d_in[11];
  float* out = (float*)d_out;

  char* wsb = (char*)d_ws;
  size_t off = 0;
  u16* xbf    = (u16*)(wsb + off); off += (size_t)MM * DDIM * 2;   // 32 MB
  u16* wfus   = (u16*)(wsb + off); off += 12ull * DDSQ * 2;        // 24 MB
  u16* wobf   = (u16*)(wsb + off); off += DDSQ * 2;                // 2 MB
  float* bfus = (float*)(wsb + off); off += 65536;                 // 48 KB + pad
  u16* combc  = (u16*)(wsb + off); off += (size_t)MM * DDIM * 2;   // 32 MB
  char* dynr  = wsb + off;
  size_t fixed = off;

  int chunk = 4096;
  while (chunk > 1024 && fixed + (size_t)12 * chunk * DDIM * 2 > ws_size)
    chunk >>= 1;
  u16* projc = (u16*)dynr;
  u16* wtT  = (u16*)dynr;                      // prefuse overlay, 6 MB
  u16* wsbf = (u16*)(dynr + 3ull * DDSQ * 2);  // prefuse overlay, 8 MB

  // fused conversions: x, ws, wo -> bf16 (one kernel)
  k_cvt3<<<2048, 256, 0, stream>>>(
      x, xbf, MM * DDIM / 4,
      ws, wsbf, (int)(4 * DDSQ / 4),
      wo, wobf, (int)(DDSQ / 4));

  k_transpose_bf16<<<dim3(32, 32, 3), dim3(32, 8), 0, stream>>>(wq, wk, wv, wtT);
  k_bias_fuse<<<dim3(256, 12), 256, 0, stream>>>(ws, bq, bk, bv, bs, bfus);

  // fused weights: Wf[s*3+t] = ws_bf[s] @ wtT[t]^T  (pipelined, ZMODE=1)
  k_gemm256<u16, 1><<<dim3(48, 4), 512, 0, stream>>>(
      wsbf, wtT, wfus, nullptr, 1024, 1024, 1024, DDSQ, DDSQ, DDSQ, 0, 4);

  // chunked: proj (12 batched, ZMODE=0 — round-12-identical) -> attention
  int nchunks = MM / chunk;
  for (int c = 0; c < nchunks; ++c) {
    const u16* xa = xbf + (size_t)c * chunk * DDIM;
    k_gemm256<u16, 0><<<dim3(48, chunk / 256), 512, 0, stream>>>(
        xa, wfus, projc, bfus, chunk, 1024, 1024,
        0, DDSQ, (size_t)chunk * DDIM, DDIM, 4);
    k_attn_all<<<dim3(chunk / 4), 256, 0, stream>>>(
        projc, combc + (size_t)c * chunk * DDIM, sl, chunk);
  }

  // single final GEMM: out = comb_bf @ wo^T + bo  (fp32 out)
  k_gemm256<float, 0><<<dim3(4, 64), 512, 0, stream>>>(
      combc, wobf, out, bo, MM, 1024, 1024, 0, 0, 0, 0, 4);
}

// Round 16
// 653.679 us; speedup vs baseline: 1.0946x; 1.0463x over previous
//
#include <hip/hip_runtime.h>

// ---------------------------------------------------------------------------
// FractalAttention: B=4, L=4096, D=1024, H=16, DH=64, S=4
//
//  sq_s = x @ (ws[s]@wq).T + (ws[s]@bq + bs[s])   (same for k,v)
//  1. convert x, ws, wo to bf16 (one fused kernel); transpose wq/wk/wv
//  2. fuse weights:  Wf[s*3+t] = ws[s] @ w_t   (gemm256<ZMODE=1>)
//  3. fuse biases:   bf[s*3+t] = ws_bf16[s] @ b_t + bs[s]
//  4. per row-chunk: proj (12 batched, gemm256<ZMODE=0>) -> all-scale fused
//     attention (rolled + LDS K/V double-buffer; QK^T via v_dot2_f32_bf16
//     when available, __has_builtin-guarded fallback to scalar path)
//  5. single final GEMM: out = comb @ wo.T + bo  (gemm256<float,0>)
//
// Experiment ledger (do not retry):
//  - proj structures, all 105-115us / 38-43% util: m97-128^2 134; 2-phase
//    256^2 115; merged-1-barrier 108.7; reg-dbuf 105.5 (BEST); +SGB 114;
//    8-phase m201-port 111/40%.
//  - RUNTIME zmode param on gemm256: +10%/dispatch codegen tax (r14) —
//    compile-time template only.
//  - 2 blk/CU @256^2 impossible (acc=128 VGPR > cap at 4 waves/EU).
//  - per-lane gathered global loads serialize TA (~2000cyc/tile, r11).
//  - unrolled attn scale loop spills (256 VGPR / 200MB scratch, r6/r8).
// ---------------------------------------------------------------------------

typedef unsigned short u16;
typedef __attribute__((ext_vector_type(8))) short s16x8;
typedef __attribute__((ext_vector_type(8))) unsigned short u16x8;
typedef __attribute__((ext_vector_type(4))) float f32x4;

#if defined(__has_builtin)
#if __has_builtin(__builtin_amdgcn_fdot2_f32_bf16)
#define USE_DOT2 1
#endif
#endif

#ifdef USE_DOT2
typedef __attribute__((ext_vector_type(2))) __bf16 bf16x2;
__device__ __forceinline__ bf16x2 bc2(unsigned u) {
  return __builtin_bit_cast(bf16x2, u);
}
__device__ __forceinline__ float dot2bf(unsigned a, unsigned b, float c) {
  return __builtin_amdgcn_fdot2_f32_bf16(bc2(a), bc2(b), c, false);
}
#endif

#define MM 16384        // B*L
#define DDIM 1024
#define DDSQ 1048576ull // D*D

__device__ __forceinline__ u16 f2bf(float f) {
  unsigned u = __float_as_uint(f);
  u = (u + 0x7FFFu + ((u >> 16) & 1u)) >> 16;   // RNE
  return (u16)u;
}
__device__ __forceinline__ float b2f(u16 b) {
  return __uint_as_float(((unsigned)b) << 16);
}
__device__ __forceinline__ void gload_lds16(const void* g, void* l) {
  __builtin_amdgcn_global_load_lds(
      (const __attribute__((address_space(1))) void*)g,
      (__attribute__((address_space(3))) void*)l, 16, 0, 0);
}

// ---------------------------------------------------------------------------
// fused f32 -> bf16 convert for three arrays (grid-stride, float4 units)
// ---------------------------------------------------------------------------
__global__ __launch_bounds__(256) void k_cvt3(
    const float* __restrict__ a, u16* __restrict__ oa, int na,
    const float* __restrict__ b, u16* __restrict__ ob, int nb,
    const float* __restrict__ c, u16* __restrict__ oc, int nc) {
  int total = na + nb + nc;
  for (int i = blockIdx.x * 256 + threadIdx.x; i < total;
       i += gridDim.x * 256) {
    const float* src; u16* dst; int j = i;
    if (j < na)            { src = a; dst = oa; }
    else if ((j -= na) < nb) { src = b; dst = ob; }
    else                   { j -= nb; src = c; dst = oc; }
    float4 v = reinterpret_cast<const float4*>(src)[j];
    ushort4 o;
    o.x = f2bf(v.x); o.y = f2bf(v.y); o.z = f2bf(v.z); o.w = f2bf(v.w);
    reinterpret_cast<ushort4*>(dst)[j] = o;
  }
}

// ---------------------------------------------------------------------------
__global__ __launch_bounds__(256) void k_transpose_bf16(
    const float* __restrict__ wq, const float* __restrict__ wk,
    const float* __restrict__ wv, u16* __restrict__ out) {
  __shared__ float tile[32][33];
  const float* src = (blockIdx.z == 0) ? wq : (blockIdx.z == 1) ? wk : wv;
  u16* dst = out + (size_t)blockIdx.z * DDSQ;
  int tx = threadIdx.x, ty = threadIdx.y;
  int bx = blockIdx.x * 32, by = blockIdx.y * 32;
#pragma unroll
  for (int i = 0; i < 4; ++i)
    tile[ty + 8 * i][tx] = src[(size_t)(by + ty + 8 * i) * DDIM + bx + tx];
  __syncthreads();
#pragma unroll
  for (int i = 0; i < 4; ++i)
    dst[(size_t)(bx + ty + 8 * i) * DDIM + by + tx] = f2bf(tile[tx][ty + 8 * i]);
}

// ---------------------------------------------------------------------------
// fused bias from bf16 ws (halves ws re-read; with zero b vectors the dot
// is exactly 0 either way, so bfus = bs bit-identically)
// ---------------------------------------------------------------------------
__global__ __launch_bounds__(256) void k_bias_fuse(
    const u16* __restrict__ wsbf, const float* __restrict__ bq,
    const float* __restrict__ bk, const float* __restrict__ bv,
    const float* __restrict__ bs, float* __restrict__ bf) {
  int idx = blockIdx.y;
  int s = idx / 3, t = idx - s * 3;
  const float* bt = (t == 0) ? bq : (t == 1) ? bk : bv;
  int lane = threadIdx.x & 63, wid = threadIdx.x >> 6;
  int e = blockIdx.x * 4 + wid;
  const u16* wr = wsbf + (size_t)s * DDSQ + (size_t)e * DDIM;
  float p = 0.f;
  for (int j0 = lane * 8; j0 < DDIM; j0 += 512) {
    u16x8 w8 = *reinterpret_cast<const u16x8*>(wr + j0);
#pragma unroll
    for (int i = 0; i < 8; ++i) p = fmaf(b2f(w8[i]), bt[j0 + i], p);
  }
#pragma unroll
  for (int off = 32; off > 0; off >>= 1) p += __shfl_xor(p, off);
  if (lane == 0) bf[idx * DDIM + e] = p + bs[s * DDIM + e];
}

// ---------------------------------------------------------------------------
// Round-7/12 256x256 pipelined GEMM (16x16 MFMA, ring-4, reg-dbuf ds_reads).
// Known good: 105.5us proj-class, MfmaUtil 43%, conflicts 0.
// ZMODE is COMPILE-TIME (r14 lesson: runtime zmode cost 10%/dispatch).
// ---------------------------------------------------------------------------
template <typename OutT, int ZMODE>
__global__ __launch_bounds__(512, 1) void k_gemm256(
    const u16* __restrict__ A, const u16* __restrict__ B, OutT* __restrict__ C,
    const float* __restrict__ bias, int M, int N, int K,
    size_t za, size_t zb, size_t zc, size_t zbias, int nbx) {
  __shared__ u16 lds[4][2][8192];   // [ring][A/B][256*32]

  int z = blockIdx.x / nbx;
  int nb = blockIdx.x - z * nbx;
  const u16* Ag; const u16* Bg;
  if constexpr (ZMODE == 1) {
    Ag = A + (size_t)(z / 3) * za; Bg = B + (size_t)(z % 3) * zb;
  } else {
    Ag = A + (size_t)z * za;       Bg = B + (size_t)z * zb;
  }
  OutT* Cg = C + (size_t)z * zc;
  const float* biasz = nullptr;
  if constexpr (ZMODE == 0) biasz = bias + (size_t)z * zbias;

  int m0 = blockIdx.y * 256, n0 = nb * 256;
  int tid = threadIdx.x;
  int lane = tid & 63, wid = tid >> 6;
  int wm = wid >> 2, wn = wid & 3;
  int NT = K >> 5;

  int scb = ((lane & 3) * 16) ^ (((lane >> 3) & 3) << 4);
  const char* srcA[2]; const char* srcB[2]; int ldsc[2];
#pragma unroll
  for (int r = 0; r < 2; ++r) {
    int c = r * 8 + wid;
    int row = c * 16 + (lane >> 2);
    srcA[r] = (const char*)Ag + ((size_t)(m0 + row) * K) * 2 + scb;
    srcB[r] = (const char*)Bg + ((size_t)(n0 + row) * K) * 2 + scb;
    ldsc[r] = c * 1024;
  }
  char* lbase = (char*)&lds[0][0][0];

  int fxor = ((lane >> 4) * 16) ^ (((lane >> 1) & 3) << 4);
  int aoff = (wm * 128 + (lane & 15)) * 64 + fxor;
  int boff = (wn * 64 + (lane & 15)) * 64 + fxor;

  f32x4 acc[8][4] = {};
  s16x8 cA0[4], cA1[4], cB[4];
  s16x8 nA0[4], nA1[4], nB[4];

#define STAGE_A(kt, rg)                                                   \
  {                                                                       \
    _Pragma("unroll") for (int r = 0; r < 2; ++r)                         \
        gload_lds16(srcA[r] + (size_t)(kt) * 64,                          \
                    lbase + (rg) * 32768 + ldsc[r]);                      \
  }
#define STAGE_B(kt, rg)                                                   \
  {                                                                       \
    _Pragma("unroll") for (int r = 0; r < 2; ++r)                         \
        gload_lds16(srcB[r] + (size_t)(kt) * 64,                          \
                    lbase + (rg) * 32768 + 16384 + ldsc[r]);              \
  }
#define SUBITER(C0, C1, CBv, N0, N1, NBv, tcur)                           \
  {                                                                       \
    asm volatile("s_waitcnt vmcnt(4)" ::: "memory");                      \
    asm volatile("s_barrier" ::: "memory");                               \
    int tn = (tcur) + 1 < NT ? (tcur) + 1 : NT - 1;                       \
    const char* bA = lbase + (tn & 3) * 32768;                            \
    const char* bB = bA + 16384;                                          \
    _Pragma("unroll") for (int i = 0; i < 4; ++i)                         \
        NBv[i] = *(const s16x8*)(bB + boff + i * 1024);                   \
    _Pragma("unroll") for (int i = 0; i < 4; ++i)                         \
        N0[i] = *(const s16x8*)(bA + aoff + i * 1024);                    \
    _Pragma("unroll") for (int i = 0; i < 4; ++i)                         \
        N1[i] = *(const s16x8*)(bA + aoff + 4096 + i * 1024);             \
    int ts = (tcur) + 3 < NT ? (tcur) + 3 : NT - 1;                       \
    int rgs = ((tcur) + 3) & 3;                                           \
    STAGE_A(ts, rgs); STAGE_B(ts, rgs);                                   \
    __builtin_amdgcn_s_setprio(1);                                        \
    _Pragma("unroll") for (int mi = 0; mi < 4; ++mi)                      \
      _Pragma("unroll") for (int ni = 0; ni < 4; ++ni)                    \
          acc[mi][ni] = __builtin_amdgcn_mfma_f32_16x16x32_bf16(          \
              C0[mi], CBv[ni], acc[mi][ni], 0, 0, 0);                     \
    _Pragma("unroll") for (int mi = 0; mi < 4; ++mi)                      \
      _Pragma("unroll") for (int ni = 0; ni < 4; ++ni)                    \
          acc[mi + 4][ni] = __builtin_amdgcn_mfma_f32_16x16x32_bf16(      \
              C1[mi], CBv[ni], acc[mi + 4][ni], 0, 0, 0);                 \
    __builtin_amdgcn_s_setprio(0);                                        \
  }

  STAGE_A(0, 0); STAGE_B(0, 0);
  STAGE_A(1, 1); STAGE_B(1, 1);
  STAGE_A(2, 2); STAGE_B(2, 2);
  asm volatile("s_waitcnt vmcnt(8)" ::: "memory");
  asm volatile("s_barrier" ::: "memory");
  {
    const char* bA = lbase;
    const char* bB = bA + 16384;
#pragma unroll
    for (int i = 0; i < 4; ++i) cB[i]  = *(const s16x8*)(bB + boff + i * 1024);
#pragma unroll
    for (int i = 0; i < 4; ++i) cA0[i] = *(const s16x8*)(bA + aoff + i * 1024);
#pragma unroll
    for (int i = 0; i < 4; ++i)
      cA1[i] = *(const s16x8*)(bA + aoff + 4096 + i * 1024);
  }

  for (int t = 0; t < NT; t += 2) {
    SUBITER(cA0, cA1, cB, nA0, nA1, nB, t);
    SUBITER(nA0, nA1, nB, cA0, cA1, cB, t + 1);
  }
#undef SUBITER
#undef STAGE_A
#undef STAGE_B

  asm volatile("s_waitcnt vmcnt(0)" ::: "memory");

#pragma unroll
  for (int mi = 0; mi < 8; ++mi) {
#pragma unroll
    for (int ni = 0; ni < 4; ++ni) {
      int colg = n0 + wn * 64 + ni * 16 + (lane & 15);
      float badd;
      if constexpr (ZMODE == 0) badd = biasz[colg];
      else                      badd = 0.f;
#pragma unroll
      for (int r = 0; r < 4; ++r) {
        int rowg = m0 + wm * 128 + mi * 16 + ((lane >> 4) << 2) + r;
        float v = acc[mi][ni][r] + badd;
        if constexpr (sizeof(OutT) == 2) Cg[(size_t)rowg * N + colg] = f2bf(v);
        else                             Cg[(size_t)rowg * N + colg] = v;
      }
    }
  }
}

// ---------------------------------------------------------------------------
// per-position head-mix attention, ALL 4 scales fused. (round-12 structure:
// rolled loop + LDS K/V double-buffer, vmcnt(6). Do not unroll.)
// QK^T via v_dot2_f32_bf16 when available (q/K are bf16 already; each LDS
// dword is a ready bf16x2 operand — zero repack). 0.125 applied after the
// reduce (exact pow2 scale).
// ---------------------------------------------------------------------------
__global__ __launch_bounds__(256) void k_attn_all(
    const u16* __restrict__ proj, u16* __restrict__ outbf,
    const float* __restrict__ sl, int rows) {
  __shared__ u16 kv[4][2][2][1024];   // [wave][buf][K/V][1024] = 32 KB
  int lane = threadIdx.x & 63, wid = threadIdx.x >> 6;
  int row = blockIdx.x * 4 + wid;
  int h = lane >> 2, dq = lane & 3;
  int doff = h * 64 + dq * 16;

  float l0 = sl[0], l1 = sl[1], l2 = sl[2], l3 = sl[3];
  float lm = fmaxf(fmaxf(l0, l1), fmaxf(l2, l3));
  float e0 = __expf(l0 - lm), e1 = __expf(l1 - lm), e2 = __expf(l2 - lm),
        e3 = __expf(l3 - lm);
  float esum = e0 + e1 + e2 + e3;
  float wsc4[4] = {e0 / esum, e1 / esum, e2 / esum, e3 / esum};

#define KV_ISSUE(s, buf)                                                   \
  {                                                                        \
    const u16* kr = proj + ((size_t)(3 * (s) + 1) * rows + row) * DDIM;    \
    const u16* vr = proj + ((size_t)(3 * (s) + 2) * rows + row) * DDIM;    \
    gload_lds16(kr + lane * 8,       &kv[wid][buf][0][0]);                 \
    gload_lds16(kr + 512 + lane * 8, &kv[wid][buf][0][512]);               \
    gload_lds16(vr + lane * 8,       &kv[wid][buf][1][0]);                 \
    gload_lds16(vr + 512 + lane * 8, &kv[wid][buf][1][512]);               \
  }

  KV_ISSUE(0, 0);   // prologue: scale 0 -> buf 0

  float acc[16];
#pragma unroll
  for (int i = 0; i < 16; ++i) acc[i] = 0.f;

  for (int s = 0; s < 4; ++s) {
    int buf = s & 1;

    const u16* qr = proj + ((size_t)(3 * s) * rows + row) * DDIM + doff;
#ifdef USE_DOT2
    uint4 qa = *reinterpret_cast<const uint4*>(qr);
    uint4 qb = *reinterpret_cast<const uint4*>(qr + 8);
#else
    u16x8 q0 = *reinterpret_cast<const u16x8*>(qr);
    u16x8 q1 = *reinterpret_cast<const u16x8*>(qr + 8);
#endif

    if (s < 3) KV_ISSUE(s + 1, buf ^ 1);

    if (s < 3) asm volatile("s_waitcnt vmcnt(6)" ::: "memory");
    else       asm volatile("s_waitcnt vmcnt(0)" ::: "memory");

#ifndef USE_DOT2
    float qf[16];
#pragma unroll
    for (int i = 0; i < 8; ++i) {
      qf[i]     = b2f(q0[i]) * 0.125f;
      qf[8 + i] = b2f(q1[i]) * 0.125f;
    }
#endif

    float sc[16];
#pragma unroll
    for (int g = 0; g < 16; ++g) {
      const u16* kp = &kv[wid][buf][0][g * 64 + dq * 16];
#ifdef USE_DOT2
      uint4 ka = *reinterpret_cast<const uint4*>(kp);
      uint4 kb = *reinterpret_cast<const uint4*>(kp + 8);
      float d = 0.f;
      d = dot2bf(ka.x, qa.x, d);
      d = dot2bf(ka.y, qa.y, d);
      d = dot2bf(ka.z, qa.z, d);
      d = dot2bf(ka.w, qa.w, d);
      d = dot2bf(kb.x, qb.x, d);
      d = dot2bf(kb.y, qb.y, d);
      d = dot2bf(kb.z, qb.z, d);
      d = dot2bf(kb.w, qb.w, d);
      d += __shfl_xor(d, 1);
      d += __shfl_xor(d, 2);
      sc[g] = d * 0.125f;
#else
      u16x8 k0 = *reinterpret_cast<const u16x8*>(kp);
      u16x8 k1 = *reinterpret_cast<const u16x8*>(kp + 8);
      float d = 0.f;
#pragma unroll
      for (int i = 0; i < 8; ++i) d = fmaf(qf[i], b2f(k0[i]), d);
#pragma unroll
      for (int i = 0; i < 8; ++i) d = fmaf(qf[8 + i], b2f(k1[i]), d);
      d += __shfl_xor(d, 1);
      d += __shfl_xor(d, 2);
      sc[g] = d;
#endif
    }

    float mx = sc[0];
#pragma unroll
    for (int g = 1; g < 16; ++g) mx = fmaxf(mx, sc[g]);
    float sum = 0.f;
#pragma unroll
    for (int g = 0; g < 16; ++g) { sc[g] = __expf(sc[g] - mx); sum += sc[g]; }
    float inv = wsc4[s] / sum;
#pragma unroll
    for (int g = 0; g < 16; ++g) sc[g] *= inv;

#pragma unroll
    for (int g = 0; g < 16; ++g) {
      float a = sc[g];
      const u16* vp = &kv[wid][buf][1][g * 64 + dq * 16];
      u16x8 v0 = *reinterpret_cast<const u16x8*>(vp);
      u16x8 v1 = *reinterpret_cast<const u16x8*>(vp + 8);
#pragma unroll
      for (int i = 0; i < 8; ++i) {
        acc[i]     = fmaf(a, b2f(v0[i]), acc[i]);
        acc[8 + i] = fmaf(a, b2f(v1[i]), acc[8 + i]);
      }
    }
  }
#undef KV_ISSUE

  u16* op = outbf + (size_t)row * DDIM + doff;
  u16x8 o0, o1;
#pragma unroll
  for (int i = 0; i < 8; ++i) {
    o0[i] = f2bf(acc[i]);
    o1[i] = f2bf(acc[8 + i]);
  }
  *reinterpret_cast<u16x8*>(op) = o0;
  *reinterpret_cast<u16x8*>(op + 8) = o1;
}

// ---------------------------------------------------------------------------
extern "C" void kernel_launch(void* const* d_in, const int* in_sizes, int n_in,
                              void* d_out, int out_size, void* d_ws,
                              size_t ws_size, hipStream_t stream) {
  const float* x  = (const float*)d_in[0];
  const float* sl = (const float*)d_in[1];
  const float* wq = (const float*)d_in[2];
  const float* bq = (const float*)d_in[3];
  const float* wk = (const float*)d_in[4];
  const float* bk = (const float*)d_in[5];
  const float* wv = (const float*)d_in[6];
  const float* bv = (const float*)d_in[7];
  const float* wo = (const float*)d_in[8];
  const float* bo = (const float*)d_in[9];
  const float* ws = (const float*)d_in[10];
  const float* bs = (const float*)d_in[11];
  float* out = (float*)d_out;

  char* wsb = (char*)d_ws;
  size_t off = 0;
  u16* xbf    = (u16*)(wsb + off); off += (size_t)MM * DDIM * 2;   // 32 MB
  u16* wfus   = (u16*)(wsb + off); off += 12ull * DDSQ * 2;        // 24 MB
  u16* wobf   = (u16*)(wsb + off); off += DDSQ * 2;                // 2 MB
  float* bfus = (float*)(wsb + off); off += 65536;                 // 48 KB + pad
  u16* combc  = (u16*)(wsb + off); off += (size_t)MM * DDIM * 2;   // 32 MB
  char* dynr  = wsb + off;
  size_t fixed = off;

  int chunk = 4096;
  while (chunk > 1024 && fixed + (size_t)12 * chunk * DDIM * 2 > ws_size)
    chunk >>= 1;
  u16* projc = (u16*)dynr;
  u16* wtT  = (u16*)dynr;                      // prefuse overlay, 6 MB
  u16* wsbf = (u16*)(dynr + 3ull * DDSQ * 2);  // prefuse overlay, 8 MB

  // fused conversions: x, ws, wo -> bf16 (one kernel)
  k_cvt3<<<2048, 256, 0, stream>>>(
      x, xbf, MM * DDIM / 4,
      ws, wsbf, (int)(4 * DDSQ / 4),
      wo, wobf, (int)(DDSQ / 4));

  k_transpose_bf16<<<dim3(32, 32, 3), dim3(32, 8), 0, stream>>>(wq, wk, wv, wtT);
  k_bias_fuse<<<dim3(256, 12), 256, 0, stream>>>(wsbf, bq, bk, bv, bs, bfus);

  // fused weights: Wf[s*3+t] = ws_bf[s] @ wtT[t]^T  (pipelined, ZMODE=1)
  k_gemm256<u16, 1><<<dim3(48, 4), 512, 0, stream>>>(
      wsbf, wtT, wfus, nullptr, 1024, 1024, 1024, DDSQ, DDSQ, DDSQ, 0, 4);

  // chunked: proj (12 batched, ZMODE=0) -> fused attention
  int nchunks = MM / chunk;
  for (int c = 0; c < nchunks; ++c) {
    const u16* xa = xbf + (size_t)c * chunk * DDIM;
    k_gemm256<u16, 0><<<dim3(48, chunk / 256), 512, 0, stream>>>(
        xa, wfus, projc, bfus, chunk, 1024, 1024,
        0, DDSQ, (size_t)chunk * DDIM, DDIM, 4);
    k_attn_all<<<dim3(chunk / 4), 256, 0, stream>>>(
        projc, combc + (size_t)c * chunk * DDIM, sl, chunk);
  }

  // single final GEMM: out = comb_bf @ wo^T + bo  (fp32 out)
  k_gemm256<float, 0><<<dim3(4, 64), 512, 0, stream>>>(
      combc, wobf, out, bo, MM, 1024, 1024, 0, 0, 0, 0, 4);
}